// Round 1
// baseline (123.884 us; speedup 1.0000x reference)
//
#include <hip/hip_runtime.h>

#define EPS 1e-12f

constexpr int D = 1024;   // feature dim
constexpr int K = 16;     // centers per class

// ---------------------------------------------------------------------------
// Kernel 1: per-(class,k) center inverse norms -> ws, and zero the output.
// One wave (64 lanes) per center row. nrows = C*K = 1440.
// ---------------------------------------------------------------------------
__global__ __launch_bounds__(256) void center_norms_kernel(
    const float* __restrict__ centers, float* __restrict__ cinv,
    float* __restrict__ out, int nrows) {
    if (blockIdx.x == 0 && threadIdx.x == 0) out[0] = 0.0f;

    const int wave = (blockIdx.x * blockDim.x + threadIdx.x) >> 6;
    const int lane = threadIdx.x & 63;
    if (wave >= nrows) return;

    const float* row = centers + (size_t)wave * D;
    float acc = 0.0f;
#pragma unroll
    for (int j = 0; j < 4; ++j) {
        float4 v = *reinterpret_cast<const float4*>(row + j * 256 + lane * 4);
        acc += v.x * v.x + v.y * v.y + v.z * v.z + v.w * v.w;
    }
#pragma unroll
    for (int off = 32; off >= 1; off >>= 1) acc += __shfl_xor(acc, off, 64);

    if (lane == 0) cinv[wave] = 1.0f / sqrtf(acc + EPS);
}

// ---------------------------------------------------------------------------
// Kernel 2: one wave per sample. Raw dots x . c_k for k=0..15 plus x.x,
// all accumulated in registers, one butterfly reduction, tiny epilogue,
// per-block combine, one atomicAdd per block.
// ---------------------------------------------------------------------------
__global__ __launch_bounds__(256) void cosine_loss_kernel(
    const float* __restrict__ x, const int* __restrict__ labels,
    const float* __restrict__ centers, const float* __restrict__ cinv,
    float* __restrict__ out, int B, float inv_B) {
    const int wave_in_blk = threadIdx.x >> 6;
    const int lane        = threadIdx.x & 63;
    const int sample      = blockIdx.x * 4 + wave_in_blk;

    __shared__ float partials[4];

    float per_sample = 0.0f;
    if (sample < B) {
        const float* xrow = x + (size_t)sample * D;

        // Load the x-row fragment: lane covers float4 at (j*64 + lane)*4 floats.
        float4 xf[4];
        float xx = 0.0f;
#pragma unroll
        for (int j = 0; j < 4; ++j) {
            xf[j] = *reinterpret_cast<const float4*>(xrow + j * 256 + lane * 4);
            xx += xf[j].x * xf[j].x + xf[j].y * xf[j].y +
                  xf[j].z * xf[j].z + xf[j].w * xf[j].w;
        }

        const int label = labels[sample];
        const float* crow = centers + (size_t)label * K * D;

        float dot[K];
#pragma unroll
        for (int k = 0; k < K; ++k) {
            float acc = 0.0f;
#pragma unroll
            for (int j = 0; j < 4; ++j) {
                float4 c = *reinterpret_cast<const float4*>(
                    crow + k * D + j * 256 + lane * 4);
                acc += c.x * xf[j].x + c.y * xf[j].y +
                       c.z * xf[j].z + c.w * xf[j].w;
            }
            dot[k] = acc;
        }

        // Butterfly-reduce all 17 accumulators across the 64-lane wave.
#pragma unroll
        for (int off = 32; off >= 1; off >>= 1) {
            xx += __shfl_xor(xx, off, 64);
#pragma unroll
            for (int k = 0; k < K; ++k) dot[k] += __shfl_xor(dot[k], off, 64);
        }

        if (lane == 0) {
            const float nx_inv = 1.0f / sqrtf(xx + EPS);
            const float* ci = cinv + label * K;
            float sum_d = 0.0f, sum_d2 = 0.0f;
#pragma unroll
            for (int k = 0; k < K; ++k) {
                float s  = dot[k] * nx_inv * ci[k];
                float dk = 1.0f - s;
                sum_d  += dk;
                sum_d2 += dk * dk;
            }
            per_sample = sum_d - sum_d2 / sum_d;
        }
    }

    if (lane == 0) partials[wave_in_blk] = per_sample;
    __syncthreads();
    if (threadIdx.x == 0) {
        float blk = (partials[0] + partials[1]) + (partials[2] + partials[3]);
        atomicAdd(out, blk * inv_B);
    }
}

// ---------------------------------------------------------------------------
extern "C" void kernel_launch(void* const* d_in, const int* in_sizes, int n_in,
                              void* d_out, int out_size, void* d_ws, size_t ws_size,
                              hipStream_t stream) {
    const float* x       = (const float*)d_in[0];
    const int*   labels  = (const int*)d_in[1];
    const float* centers = (const float*)d_in[2];

    const int B     = in_sizes[1];              // 8192
    const int nrows = in_sizes[2] / D;          // C*K = 1440

    float* out  = (float*)d_out;
    float* cinv = (float*)d_ws;                 // C*K floats of scratch

    // Kernel 1: center inverse norms (one wave per row) + zero output.
    const int blocks1 = (nrows + 3) / 4;
    center_norms_kernel<<<blocks1, 256, 0, stream>>>(centers, cinv, out, nrows);

    // Kernel 2: one wave per sample.
    const int blocks2 = (B + 3) / 4;
    cosine_loss_kernel<<<blocks2, 256, 0, stream>>>(
        x, labels, centers, cinv, out, B, 1.0f / (float)B);
}